// Round 7
// baseline (132.624 us; speedup 1.0000x reference)
//
#include <hip/hip_runtime.h>

// KroneSoftmax: x[2, 2048, 256] fp32.
// out[b, a*256+k] = softmax_row( x[0][b,a] * x[1][b,k] )
// Round 6: K1 reduce -> C[row]; K2 DENSE-SWEEP store: wave w writes 1KB
// chunk g = w + t*8192, so the instantaneous GPU-wide write front is one
// contiguous ~8MB window sweeping the 536MB output sequentially (mimics the
// grid-stride fill kernel that hits 6.7 TB/s). Per-iter row reloads are
// L2/L3-hot (4MB input) with depth-1 register prefetch.

constexpr int FA   = 256;
constexpr int FB   = 256;
constexpr int ROWS = 2048;
constexpr int NCHUNK = ROWS * FA;        // 524288 1KB chunks
constexpr int NWAVE  = 8192;             // 2048 blocks * 4 waves
constexpr float LOG2E = 1.4426950408889634f;

typedef float f32x4 __attribute__((ext_vector_type(4)));

// ---------------- K1: per-row reduction -> C[row] ----------------
__global__ __launch_bounds__(256) void krone_reduce_kernel(
    const float* __restrict__ x, float* __restrict__ Cbuf) {
  const int row = blockIdx.x;
  const int tid = threadIdx.x;

  const float* __restrict__ xa = x + (size_t)row * FA;
  const float* __restrict__ xb = x + (size_t)ROWS * FA + (size_t)row * FB;

  __shared__ float sa[FA];
  __shared__ float wred[4][4];
  __shared__ float wsum[4];

  const float a = xa[tid];
  const float b = xb[tid];
  sa[tid] = a;

  float maxa = a, mina = a, maxb = b, minb = b;
#pragma unroll
  for (int off = 32; off > 0; off >>= 1) {
    maxa = fmaxf(maxa, __shfl_xor(maxa, off));
    mina = fminf(mina, __shfl_xor(mina, off));
    maxb = fmaxf(maxb, __shfl_xor(maxb, off));
    minb = fminf(minb, __shfl_xor(minb, off));
  }
  const int wid = tid >> 6;
  if ((tid & 63) == 0) {
    wred[wid][0] = maxa; wred[wid][1] = mina;
    wred[wid][2] = maxb; wred[wid][3] = minb;
  }
  __syncthreads();
  const float MA = fmaxf(fmaxf(wred[0][0], wred[1][0]), fmaxf(wred[2][0], wred[3][0]));
  const float mA = fminf(fminf(wred[0][1], wred[1][1]), fminf(wred[2][1], wred[3][1]));
  const float MB = fmaxf(fmaxf(wred[0][2], wred[1][2]), fmaxf(wred[2][2], wred[3][2]));
  const float mB = fminf(fminf(wred[0][3], wred[1][3]), fminf(wred[2][3], wred[3][3]));
  const float M = fmaxf(fmaxf(MA * MB, MA * mB), fmaxf(mA * MB, mA * mB));
  const float mM2 = -M * LOG2E;

  const float bs = b * LOG2E;
  float s0 = 0.f, s1 = 0.f, s2 = 0.f, s3 = 0.f;
#pragma unroll 4
  for (int i = 0; i < FA; i += 4) {
    s0 += __builtin_amdgcn_exp2f(fmaf(sa[i + 0], bs, mM2));
    s1 += __builtin_amdgcn_exp2f(fmaf(sa[i + 1], bs, mM2));
    s2 += __builtin_amdgcn_exp2f(fmaf(sa[i + 2], bs, mM2));
    s3 += __builtin_amdgcn_exp2f(fmaf(sa[i + 3], bs, mM2));
  }
  float s = (s0 + s1) + (s2 + s3);
#pragma unroll
  for (int off = 32; off > 0; off >>= 1) s += __shfl_xor(s, off);
  if ((tid & 63) == 0) wsum[wid] = s;
  __syncthreads();
  if (tid == 0) {
    const float sum = (wsum[0] + wsum[1]) + (wsum[2] + wsum[3]);
    Cbuf[row] = mM2 - __builtin_amdgcn_logf(sum);
  }
}

// ---------------- K2: dense-sweep streaming store ----------------
__global__ __launch_bounds__(256) void krone_sweep_kernel(
    const float* __restrict__ x, const float* __restrict__ Cbuf,
    float* __restrict__ out) {
  const int tid   = threadIdx.x;
  const int lane  = tid & 63;
  const int gwave = (blockIdx.x << 2) | (tid >> 6);   // 0..8191, wave-uniform
  const float* __restrict__ xb = x + (size_t)ROWS * FA;

  // prefetch t = 0
  int g   = gwave;
  int row = g >> 8, c = g & 255;
  float av = x[row * FA + c];          // wave-uniform scalar load
  float C  = Cbuf[row];                // wave-uniform scalar load
  f32x4 b4 = *reinterpret_cast<const f32x4*>(&xb[row * FB + lane * 4]);

#pragma unroll 2
  for (int t = 0; t < NCHUNK / NWAVE; ++t) {
    // depth-1 prefetch of next chunk's row data (independent of compute)
    const int gn = g + NWAVE;
    float avn = 0.f, Cn = 0.f;
    f32x4 b4n = {0.f, 0.f, 0.f, 0.f};
    if (gn < NCHUNK) {
      const int rown = gn >> 8, cn = gn & 255;
      avn = x[rown * FA + cn];
      Cn  = Cbuf[rown];
      b4n = *reinterpret_cast<const f32x4*>(&xb[rown * FB + lane * 4]);
    }

    const float avl = av * LOG2E;
    f32x4 v;
    v.x = __builtin_amdgcn_exp2f(fmaf(avl, b4.x, C));
    v.y = __builtin_amdgcn_exp2f(fmaf(avl, b4.y, C));
    v.z = __builtin_amdgcn_exp2f(fmaf(avl, b4.z, C));
    v.w = __builtin_amdgcn_exp2f(fmaf(avl, b4.w, C));
    *reinterpret_cast<f32x4*>(&out[(size_t)g * 256 + lane * 4]) = v;

    g = gn; av = avn; C = Cn; b4 = b4n;
  }
}

// ---------------- fallback: fused single kernel (ws too small) ----------------
__global__ __launch_bounds__(256) void krone_fused_kernel(
    const float* __restrict__ x, float* __restrict__ out) {
  const int row = blockIdx.x;
  const int tid = threadIdx.x;
  const float* __restrict__ xa = x + (size_t)row * FA;
  const float* __restrict__ xb = x + (size_t)ROWS * FA + (size_t)row * FB;
  __shared__ float sa[FA];
  __shared__ float sb[FB];
  __shared__ float wred[4][4];
  __shared__ float wsum[4];
  const float a = xa[tid];
  const float b = xb[tid];
  sa[tid] = a; sb[tid] = b;
  float maxa = a, mina = a, maxb = b, minb = b;
#pragma unroll
  for (int off = 32; off > 0; off >>= 1) {
    maxa = fmaxf(maxa, __shfl_xor(maxa, off));
    mina = fminf(mina, __shfl_xor(mina, off));
    maxb = fmaxf(maxb, __shfl_xor(maxb, off));
    minb = fminf(minb, __shfl_xor(minb, off));
  }
  const int wid = tid >> 6;
  if ((tid & 63) == 0) {
    wred[wid][0] = maxa; wred[wid][1] = mina;
    wred[wid][2] = maxb; wred[wid][3] = minb;
  }
  __syncthreads();
  const float MA = fmaxf(fmaxf(wred[0][0], wred[1][0]), fmaxf(wred[2][0], wred[3][0]));
  const float mA = fminf(fminf(wred[0][1], wred[1][1]), fminf(wred[2][1], wred[3][1]));
  const float MB = fmaxf(fmaxf(wred[0][2], wred[1][2]), fmaxf(wred[2][2], wred[3][2]));
  const float mB = fminf(fminf(wred[0][3], wred[1][3]), fminf(wred[2][3], wred[3][3]));
  const float M = fmaxf(fmaxf(MA * MB, MA * mB), fmaxf(mA * MB, mA * mB));
  const float mM2 = -M * LOG2E;
  const float bs = b * LOG2E;
  float s0 = 0.f, s1 = 0.f, s2 = 0.f, s3 = 0.f;
#pragma unroll 4
  for (int i = 0; i < FA; i += 4) {
    s0 += __builtin_amdgcn_exp2f(fmaf(sa[i + 0], bs, mM2));
    s1 += __builtin_amdgcn_exp2f(fmaf(sa[i + 1], bs, mM2));
    s2 += __builtin_amdgcn_exp2f(fmaf(sa[i + 2], bs, mM2));
    s3 += __builtin_amdgcn_exp2f(fmaf(sa[i + 3], bs, mM2));
  }
  float s = (s0 + s1) + (s2 + s3);
#pragma unroll
  for (int off = 32; off > 0; off >>= 1) s += __shfl_xor(s, off);
  if ((tid & 63) == 0) wsum[wid] = s;
  __syncthreads();
  const float sum = (wsum[0] + wsum[1]) + (wsum[2] + wsum[3]);
  const float C = mM2 - __builtin_amdgcn_logf(sum);
  float* __restrict__ orow = out + (size_t)row * (FA * FB);
  const int lane = tid & 63;
  const int j = lane * 4;
  f32x4 b4 = *reinterpret_cast<const f32x4*>(&sb[j]);
  b4 *= LOG2E;
  float* __restrict__ oseg = orow + wid * (64 * FB);
#pragma unroll 8
  for (int it = 0; it < 64; ++it) {
    const float av = sa[wid * 64 + it];
    f32x4 v;
    v.x = __builtin_amdgcn_exp2f(fmaf(av, b4.x, C));
    v.y = __builtin_amdgcn_exp2f(fmaf(av, b4.y, C));
    v.z = __builtin_amdgcn_exp2f(fmaf(av, b4.z, C));
    v.w = __builtin_amdgcn_exp2f(fmaf(av, b4.w, C));
    *reinterpret_cast<f32x4*>(&oseg[it * FB + j]) = v;
  }
}

extern "C" void kernel_launch(void* const* d_in, const int* in_sizes, int n_in,
                              void* d_out, int out_size, void* d_ws, size_t ws_size,
                              hipStream_t stream) {
  const float* x = (const float*)d_in[0];
  float* out = (float*)d_out;
  if (ws_size >= ROWS * sizeof(float)) {
    float* Cbuf = (float*)d_ws;
    krone_reduce_kernel<<<ROWS, 256, 0, stream>>>(x, Cbuf);
    krone_sweep_kernel<<<NWAVE / 4, 256, 0, stream>>>(x, Cbuf, out);
  } else {
    krone_fused_kernel<<<ROWS, 256, 0, stream>>>(x, out);
  }
}

// Round 8
// 127.676 us; speedup vs baseline: 1.0388x; 1.0388x over previous
//
#include <hip/hip_runtime.h>

// KroneSoftmax: x[2, 2048, 256] fp32.
// out[b, a*256+k] = softmax_row( x[0][b,a] * x[1][b,k] )
// Round 7: K1 reduce -> C[row] (unchanged). K2 = fill-shaped writer:
// 256 blocks (1/CU, 1 wave/SIMD, 1024 waves), each wave owns 2 contiguous
// rows = 512 KB unbroken write stream. All row inputs (b-fragment, C, the
// 256 a-values) are register-resident per row; store loop does zero memory
// reads. Mimics the 6.7 TB/s fill kernel's shape exactly.

constexpr int FA   = 256;
constexpr int FB   = 256;
constexpr int ROWS = 2048;
constexpr float LOG2E = 1.4426950408889634f;

typedef float f32x4 __attribute__((ext_vector_type(4)));

// ---------------- K1: per-row reduction -> C[row] ----------------
__global__ __launch_bounds__(256) void krone_reduce_kernel(
    const float* __restrict__ x, float* __restrict__ Cbuf) {
  const int row = blockIdx.x;
  const int tid = threadIdx.x;

  const float* __restrict__ xa = x + (size_t)row * FA;
  const float* __restrict__ xb = x + (size_t)ROWS * FA + (size_t)row * FB;

  __shared__ float sa[FA];
  __shared__ float wred[4][4];
  __shared__ float wsum[4];

  const float a = xa[tid];
  const float b = xb[tid];
  sa[tid] = a;

  float maxa = a, mina = a, maxb = b, minb = b;
#pragma unroll
  for (int off = 32; off > 0; off >>= 1) {
    maxa = fmaxf(maxa, __shfl_xor(maxa, off));
    mina = fminf(mina, __shfl_xor(mina, off));
    maxb = fmaxf(maxb, __shfl_xor(maxb, off));
    minb = fminf(minb, __shfl_xor(minb, off));
  }
  const int wid = tid >> 6;
  if ((tid & 63) == 0) {
    wred[wid][0] = maxa; wred[wid][1] = mina;
    wred[wid][2] = maxb; wred[wid][3] = minb;
  }
  __syncthreads();
  const float MA = fmaxf(fmaxf(wred[0][0], wred[1][0]), fmaxf(wred[2][0], wred[3][0]));
  const float mA = fminf(fminf(wred[0][1], wred[1][1]), fminf(wred[2][1], wred[3][1]));
  const float MB = fmaxf(fmaxf(wred[0][2], wred[1][2]), fmaxf(wred[2][2], wred[3][2]));
  const float mB = fminf(fminf(wred[0][3], wred[1][3]), fminf(wred[2][3], wred[3][3]));
  const float M = fmaxf(fmaxf(MA * MB, MA * mB), fmaxf(mA * MB, mA * mB));
  const float mM2 = -M * LOG2E;

  const float bs = b * LOG2E;
  float s0 = 0.f, s1 = 0.f, s2 = 0.f, s3 = 0.f;
#pragma unroll 4
  for (int i = 0; i < FA; i += 4) {
    s0 += __builtin_amdgcn_exp2f(fmaf(sa[i + 0], bs, mM2));
    s1 += __builtin_amdgcn_exp2f(fmaf(sa[i + 1], bs, mM2));
    s2 += __builtin_amdgcn_exp2f(fmaf(sa[i + 2], bs, mM2));
    s3 += __builtin_amdgcn_exp2f(fmaf(sa[i + 3], bs, mM2));
  }
  float s = (s0 + s1) + (s2 + s3);
#pragma unroll
  for (int off = 32; off > 0; off >>= 1) s += __shfl_xor(s, off);
  if ((tid & 63) == 0) wsum[wid] = s;
  __syncthreads();
  if (tid == 0) {
    const float sum = (wsum[0] + wsum[1]) + (wsum[2] + wsum[3]);
    Cbuf[row] = mM2 - __builtin_amdgcn_logf(sum);
  }
}

// ---------------- K2: fill-shaped long-stream writer ----------------
// 256 blocks x 4 waves; wave g owns rows [2g, 2g+2) => 512 KB contiguous.
__global__ __launch_bounds__(256) void krone_stream_kernel(
    const float* __restrict__ x, const float* __restrict__ Cbuf,
    float* __restrict__ out) {
  const int tid  = threadIdx.x;
  const int wid  = tid >> 6;
  const int lane = tid & 63;
  const int gw   = (blockIdx.x << 2) | wid;   // 0..1023

#pragma unroll
  for (int r = 0; r < 2; ++r) {
    const int row = gw * 2 + r;
    const float* __restrict__ xa = x + (size_t)row * FA;
    const float* __restrict__ xb = x + (size_t)ROWS * FA + (size_t)row * FB;

    f32x4 b4 = *reinterpret_cast<const f32x4*>(&xb[lane * 4]);
    b4 *= LOG2E;
    const float C = Cbuf[row];
    // register-cache the full a-row: a_cache[i] = a[i*64 + lane]
    const float a0 = xa[lane];
    const float a1 = xa[64 + lane];
    const float a2 = xa[128 + lane];
    const float a3 = xa[192 + lane];

    float* __restrict__ orow = out + (size_t)row * (FA * FB);

#define KS_BLK(I, AREG)                                                       \
    {                                                                         \
      float* __restrict__ oseg = orow + (I) * (64 * FB);                      \
      _Pragma("unroll 8")                                                     \
      for (int k = 0; k < 64; ++k) {                                          \
        const float av = __shfl(AREG, k);  /* wave-uniform broadcast */       \
        f32x4 v;                                                              \
        v.x = __builtin_amdgcn_exp2f(fmaf(av, b4.x, C));                      \
        v.y = __builtin_amdgcn_exp2f(fmaf(av, b4.y, C));                      \
        v.z = __builtin_amdgcn_exp2f(fmaf(av, b4.z, C));                      \
        v.w = __builtin_amdgcn_exp2f(fmaf(av, b4.w, C));                      \
        __builtin_nontemporal_store(                                          \
            v, reinterpret_cast<f32x4*>(&oseg[k * FB + lane * 4]));           \
      }                                                                       \
    }
    KS_BLK(0, a0)
    KS_BLK(1, a1)
    KS_BLK(2, a2)
    KS_BLK(3, a3)
#undef KS_BLK
  }
}

// ---------------- fallback: fused single kernel (ws too small) ----------------
__global__ __launch_bounds__(256) void krone_fused_kernel(
    const float* __restrict__ x, float* __restrict__ out) {
  const int row = blockIdx.x;
  const int tid = threadIdx.x;
  const float* __restrict__ xa = x + (size_t)row * FA;
  const float* __restrict__ xb = x + (size_t)ROWS * FA + (size_t)row * FB;
  __shared__ float sa[FA];
  __shared__ float sb[FB];
  __shared__ float wred[4][4];
  __shared__ float wsum[4];
  const float a = xa[tid];
  const float b = xb[tid];
  sa[tid] = a; sb[tid] = b;
  float maxa = a, mina = a, maxb = b, minb = b;
#pragma unroll
  for (int off = 32; off > 0; off >>= 1) {
    maxa = fmaxf(maxa, __shfl_xor(maxa, off));
    mina = fminf(mina, __shfl_xor(mina, off));
    maxb = fmaxf(maxb, __shfl_xor(maxb, off));
    minb = fminf(minb, __shfl_xor(minb, off));
  }
  const int wid = tid >> 6;
  if ((tid & 63) == 0) {
    wred[wid][0] = maxa; wred[wid][1] = mina;
    wred[wid][2] = maxb; wred[wid][3] = minb;
  }
  __syncthreads();
  const float MA = fmaxf(fmaxf(wred[0][0], wred[1][0]), fmaxf(wred[2][0], wred[3][0]));
  const float mA = fminf(fminf(wred[0][1], wred[1][1]), fminf(wred[2][1], wred[3][1]));
  const float MB = fmaxf(fmaxf(wred[0][2], wred[1][2]), fmaxf(wred[2][2], wred[3][2]));
  const float mB = fminf(fminf(wred[0][3], wred[1][3]), fminf(wred[2][3], wred[3][3]));
  const float M = fmaxf(fmaxf(MA * MB, MA * mB), fmaxf(mA * MB, mA * mB));
  const float mM2 = -M * LOG2E;
  const float bs = b * LOG2E;
  float s0 = 0.f, s1 = 0.f, s2 = 0.f, s3 = 0.f;
#pragma unroll 4
  for (int i = 0; i < FA; i += 4) {
    s0 += __builtin_amdgcn_exp2f(fmaf(sa[i + 0], bs, mM2));
    s1 += __builtin_amdgcn_exp2f(fmaf(sa[i + 1], bs, mM2));
    s2 += __builtin_amdgcn_exp2f(fmaf(sa[i + 2], bs, mM2));
    s3 += __builtin_amdgcn_exp2f(fmaf(sa[i + 3], bs, mM2));
  }
  float s = (s0 + s1) + (s2 + s3);
#pragma unroll
  for (int off = 32; off > 0; off >>= 1) s += __shfl_xor(s, off);
  if ((tid & 63) == 0) wsum[wid] = s;
  __syncthreads();
  const float sum = (wsum[0] + wsum[1]) + (wsum[2] + wsum[3]);
  const float C = mM2 - __builtin_amdgcn_logf(sum);
  float* __restrict__ orow = out + (size_t)row * (FA * FB);
  const int lane = tid & 63;
  const int j = lane * 4;
  f32x4 b4 = *reinterpret_cast<const f32x4*>(&sb[j]);
  b4 *= LOG2E;
  float* __restrict__ oseg = orow + wid * (64 * FB);
#pragma unroll 8
  for (int it = 0; it < 64; ++it) {
    const float av = sa[wid * 64 + it];
    f32x4 v;
    v.x = __builtin_amdgcn_exp2f(fmaf(av, b4.x, C));
    v.y = __builtin_amdgcn_exp2f(fmaf(av, b4.y, C));
    v.z = __builtin_amdgcn_exp2f(fmaf(av, b4.z, C));
    v.w = __builtin_amdgcn_exp2f(fmaf(av, b4.w, C));
    *reinterpret_cast<f32x4*>(&oseg[it * FB + j]) = v;
  }
}

extern "C" void kernel_launch(void* const* d_in, const int* in_sizes, int n_in,
                              void* d_out, int out_size, void* d_ws, size_t ws_size,
                              hipStream_t stream) {
  const float* x = (const float*)d_in[0];
  float* out = (float*)d_out;
  if (ws_size >= ROWS * sizeof(float)) {
    float* Cbuf = (float*)d_ws;
    krone_reduce_kernel<<<ROWS, 256, 0, stream>>>(x, Cbuf);
    krone_stream_kernel<<<256, 256, 0, stream>>>(x, Cbuf, out);
  } else {
    krone_fused_kernel<<<ROWS, 256, 0, stream>>>(x, out);
  }
}

// Round 9
// 105.766 us; speedup vs baseline: 1.2539x; 1.2072x over previous
//
#include <hip/hip_runtime.h>

// KroneSoftmax: x[2, 2048, 256] fp32.
// out[b, a*256+k] = softmax_row( x[0][b,a] * x[1][b,k] )
// Round 8: software-pipelined fused kernel, RPB=2 (1024 blocks, 4/CU).
// Per block: reduce(row0) -> [store(row0) WITH row1's denominator fused into
// the loop body] -> 1-barrier combine -> store(row1). Row max via wave-local
// full-row register minmax (no barriers). Removes the GPU-wide phase-aligned
// reduce head (~15us) that all previous variants exposed.

constexpr int FA   = 256;
constexpr int FB   = 256;
constexpr int ROWS = 2048;
constexpr int RPB  = 2;
constexpr float LOG2E = 1.4426950408889634f;

typedef float f32x4 __attribute__((ext_vector_type(4)));

__global__ __launch_bounds__(256) void krone_pipe_kernel(
    const float* __restrict__ x, float* __restrict__ out) {
  const int tid  = threadIdx.x;
  const int wid  = tid >> 6;
  const int lane = tid & 63;
  const int row0 = blockIdx.x * RPB;

  __shared__ float wsum[4];

  const float* __restrict__ xa0 = x + (size_t)row0 * FA;
  const float* __restrict__ xb0 = x + (size_t)ROWS * FA + (size_t)row0 * FB;
  const float* __restrict__ xa1 = xa0 + FA;
  const float* __restrict__ xb1 = xb0 + FB;

  // ---- row0 registers: wave holds the FULL a-row (ar0..ar3) ----
  const float ar0 = xa0[lane], ar1 = xa0[64 + lane];
  const float ar2 = xa0[128 + lane], ar3 = xa0[192 + lane];
  const float aw  = xa0[wid * 64 + lane];          // this wave's 64 a's
  f32x4 b4        = *(const f32x4*)&xb0[lane * 4]; // full b-row across wave
  const float bc  = xb0[wid * 64 + lane];          // lane's denom column
  // ---- row1 registers (loads issued early) ----
  const float nr0 = xa1[lane], nr1 = xa1[64 + lane];
  const float nr2 = xa1[128 + lane], nr3 = xa1[192 + lane];
  const float naw = xa1[wid * 64 + lane];
  f32x4 nb4       = *(const f32x4*)&xb1[lane * 4];
  const float nbc = xb1[wid * 64 + lane];

  // ---- wave-local exact row max (no barriers) ----
#define MINMAX_M(A0, A1, A2, A3, B4, OUTM)                                    \
  {                                                                           \
    float mxa = fmaxf(fmaxf(A0, A1), fmaxf(A2, A3));                          \
    float mna = fminf(fminf(A0, A1), fminf(A2, A3));                          \
    float mxb = fmaxf(fmaxf(B4.x, B4.y), fmaxf(B4.z, B4.w));                  \
    float mnb = fminf(fminf(B4.x, B4.y), fminf(B4.z, B4.w));                  \
    _Pragma("unroll")                                                         \
    for (int off = 32; off > 0; off >>= 1) {                                  \
      mxa = fmaxf(mxa, __shfl_xor(mxa, off));                                 \
      mna = fminf(mna, __shfl_xor(mna, off));                                 \
      mxb = fmaxf(mxb, __shfl_xor(mxb, off));                                 \
      mnb = fminf(mnb, __shfl_xor(mnb, off));                                 \
    }                                                                         \
    OUTM = fmaxf(fmaxf(mxa * mxb, mxa * mnb), fmaxf(mna * mxb, mna * mnb));   \
  }

  float M0; MINMAX_M(ar0, ar1, ar2, ar3, b4, M0);
  const float mM2_0 = -M0 * LOG2E;
  float M1; MINMAX_M(nr0, nr1, nr2, nr3, nb4, M1);
  const float mM2_1 = -M1 * LOG2E;
#undef MINMAX_M

  // ---- denominator row0 (standalone; the only exposed reduce) ----
  // lane owns column j = wid*64+lane; sum over all 256 i via register shfl.
  const float bs0 = bc * LOG2E;
  float a0 = 0.f, a1 = 0.f, a2 = 0.f, a3 = 0.f;
#define DEN64(REG)                                                            \
  _Pragma("unroll")                                                           \
  for (int m = 0; m < 64; m += 4) {                                           \
    a0 += __builtin_amdgcn_exp2f(fmaf(__shfl(REG, m + 0), bs0, mM2_0));       \
    a1 += __builtin_amdgcn_exp2f(fmaf(__shfl(REG, m + 1), bs0, mM2_0));       \
    a2 += __builtin_amdgcn_exp2f(fmaf(__shfl(REG, m + 2), bs0, mM2_0));       \
    a3 += __builtin_amdgcn_exp2f(fmaf(__shfl(REG, m + 3), bs0, mM2_0));       \
  }
  DEN64(ar0) DEN64(ar1) DEN64(ar2) DEN64(ar3)
#undef DEN64
  float part = (a0 + a1) + (a2 + a3);
#pragma unroll
  for (int off = 32; off > 0; off >>= 1) part += __shfl_xor(part, off);
  if (lane == 0) wsum[wid] = part;
  __syncthreads();
  const float sum0 = (wsum[0] + wsum[1]) + (wsum[2] + wsum[3]);
  const float C0 = mM2_0 - __builtin_amdgcn_logf(sum0);
  __syncthreads();   // wsum reuse guard

  // ---- store(row0) with row1's denominator fused in ----
  const f32x4 b4s = b4 * LOG2E;
  const float bsn = nbc * LOG2E;
  float* __restrict__ oseg0 = out + (size_t)row0 * (FA * FB) + wid * (64 * FB);
  float d0 = 0.f, d1 = 0.f, d2 = 0.f, d3 = 0.f;
#define SUBBLK(S, NREG)                                                       \
  _Pragma("unroll")                                                           \
  for (int k = 0; k < 16; ++k) {                                              \
    const int it = 16 * (S) + k;                                              \
    const float av = __shfl(aw, it);                                          \
    f32x4 v;                                                                  \
    v.x = __builtin_amdgcn_exp2f(fmaf(av, b4s.x, C0));                        \
    v.y = __builtin_amdgcn_exp2f(fmaf(av, b4s.y, C0));                        \
    v.z = __builtin_amdgcn_exp2f(fmaf(av, b4s.z, C0));                        \
    v.w = __builtin_amdgcn_exp2f(fmaf(av, b4s.w, C0));                        \
    __builtin_nontemporal_store(v, (f32x4*)&oseg0[it * FB + lane * 4]);       \
    d0 += __builtin_amdgcn_exp2f(fmaf(__shfl(NREG, 4 * k + 0), bsn, mM2_1));  \
    d1 += __builtin_amdgcn_exp2f(fmaf(__shfl(NREG, 4 * k + 1), bsn, mM2_1));  \
    d2 += __builtin_amdgcn_exp2f(fmaf(__shfl(NREG, 4 * k + 2), bsn, mM2_1));  \
    d3 += __builtin_amdgcn_exp2f(fmaf(__shfl(NREG, 4 * k + 3), bsn, mM2_1));  \
  }
  SUBBLK(0, nr0) SUBBLK(1, nr1) SUBBLK(2, nr2) SUBBLK(3, nr3)
#undef SUBBLK

  // ---- combine row1 denominator (single barrier; stores mostly drained) ----
  float partn = (d0 + d1) + (d2 + d3);
#pragma unroll
  for (int off = 32; off > 0; off >>= 1) partn += __shfl_xor(partn, off);
  if (lane == 0) wsum[wid] = partn;
  __syncthreads();
  const float sum1 = (wsum[0] + wsum[1]) + (wsum[2] + wsum[3]);
  const float C1 = mM2_1 - __builtin_amdgcn_logf(sum1);

  // ---- store(row1), plain ----
  const f32x4 nb4s = nb4 * LOG2E;
  float* __restrict__ oseg1 =
      out + (size_t)(row0 + 1) * (FA * FB) + wid * (64 * FB);
#pragma unroll 8
  for (int it = 0; it < 64; ++it) {
    const float av = __shfl(naw, it);
    f32x4 v;
    v.x = __builtin_amdgcn_exp2f(fmaf(av, nb4s.x, C1));
    v.y = __builtin_amdgcn_exp2f(fmaf(av, nb4s.y, C1));
    v.z = __builtin_amdgcn_exp2f(fmaf(av, nb4s.z, C1));
    v.w = __builtin_amdgcn_exp2f(fmaf(av, nb4s.w, C1));
    __builtin_nontemporal_store(v, (f32x4*)&oseg1[it * FB + lane * 4]);
  }
}

extern "C" void kernel_launch(void* const* d_in, const int* in_sizes, int n_in,
                              void* d_out, int out_size, void* d_ws, size_t ws_size,
                              hipStream_t stream) {
  const float* x = (const float*)d_in[0];
  float* out = (float*)d_out;
  krone_pipe_kernel<<<ROWS / RPB, 256, 0, stream>>>(x, out);
}